// Round 1
// baseline (812.747 us; speedup 1.0000x reference)
//
#include <hip/hip_runtime.h>

#define BATCH 512
#define SEQ   512
#define IN    28
#define HID   128
#define NCLS  10

__device__ __forceinline__ float fast_tanh(float x) {
    // tanh(x) = 1 - 2/(exp(2x)+1); saturates correctly at +/-inf
    float e = __expf(2.0f * x);
    return 1.0f - 2.0f * __builtin_amdgcn_rcpf(e + 1.0f);
}

__global__ __launch_bounds__(256, 2)
void rnn2_kernel(const float* __restrict__ x,
                 const float* __restrict__ W_ih0, const float* __restrict__ W_hh0,
                 const float* __restrict__ b_ih0, const float* __restrict__ b_hh0,
                 const float* __restrict__ W_ih1, const float* __restrict__ W_hh1,
                 const float* __restrict__ b_ih1, const float* __restrict__ b_hh1,
                 const float* __restrict__ W_fc,  const float* __restrict__ b_fc,
                 float* __restrict__ out)
{
    __shared__ __align__(16) float xs[SEQ * IN];     // 57344 B: whole x[b] row
    __shared__ float h0buf[2][HID];
    __shared__ float h1buf[2][HID];

    const int b    = blockIdx.x;
    const int t    = threadIdx.x;       // 0..255
    const int j    = t >> 1;            // hidden unit 0..127
    const int half = t & 1;             // which k-half this thread owns

    // ---- stage x[b,:,:] into LDS, coalesced float4 (3584 float4 / 256 thr = 14 ea)
    const float4* xg = (const float4*)(x + (size_t)b * SEQ * IN);
    float4* xl = (float4*)xs;
    #pragma unroll
    for (int i = 0; i < (SEQ * IN / 4) / 256; ++i)
        xl[t + i * 256] = xg[t + i * 256];

    // ---- weights into registers (206 floats/thread)
    float wih0[14], whh0[64], wih1[64], whh1[64];
    {
        const float* p = W_ih0 + j * IN + half * 14;
        #pragma unroll
        for (int k = 0; k < 14; ++k) wih0[k] = p[k];
    }
    {
        const float* p = W_hh0 + j * HID + half * 64;
        #pragma unroll
        for (int k = 0; k < 64; ++k) whh0[k] = p[k];
    }
    {
        const float* p = W_ih1 + j * HID + half * 64;
        #pragma unroll
        for (int k = 0; k < 64; ++k) wih1[k] = p[k];
    }
    {
        const float* p = W_hh1 + j * HID + half * 64;
        #pragma unroll
        for (int k = 0; k < 64; ++k) whh1[k] = p[k];
    }
    const float bias0 = b_ih0[j] + b_hh0[j];
    const float bias1 = b_ih1[j] + b_hh1[j];

    if (t < HID) { h0buf[0][t] = 0.0f; h1buf[0][t] = 0.0f; }
    __syncthreads();

    // ---- time loop: phase A (layer0), barrier, phase B (layer1), barrier
    for (int step = 0; step < SEQ; ++step) {
        const int rd = step & 1, wr = rd ^ 1;

        // phase A: h0(t) = tanh(W_ih0 x_t + W_hh0 h0(t-1) + bias0)
        {
            float a0 = 0.f, a1 = 0.f, a2 = 0.f, a3 = 0.f;
            const float* xt  = xs + step * IN + half * 14;
            #pragma unroll
            for (int k = 0; k < 14; k += 2) {
                a0 = fmaf(wih0[k],     xt[k],     a0);
                a1 = fmaf(wih0[k + 1], xt[k + 1], a1);
            }
            const float* h0p = &h0buf[rd][half * 64];
            #pragma unroll
            for (int k = 0; k < 64; k += 4) {
                a0 = fmaf(whh0[k],     h0p[k],     a0);
                a1 = fmaf(whh0[k + 1], h0p[k + 1], a1);
                a2 = fmaf(whh0[k + 2], h0p[k + 2], a2);
                a3 = fmaf(whh0[k + 3], h0p[k + 3], a3);
            }
            float acc = (a0 + a2) + (a1 + a3);
            acc += __shfl_xor(acc, 1);
            if (half == 0) h0buf[wr][j] = fast_tanh(acc + bias0);
        }
        __syncthreads();

        // phase B: h1(t) = tanh(W_ih1 h0(t) + W_hh1 h1(t-1) + bias1)
        {
            float a0 = 0.f, a1 = 0.f, a2 = 0.f, a3 = 0.f;
            const float* h0c = &h0buf[wr][half * 64];
            #pragma unroll
            for (int k = 0; k < 64; k += 4) {
                a0 = fmaf(wih1[k],     h0c[k],     a0);
                a1 = fmaf(wih1[k + 1], h0c[k + 1], a1);
                a2 = fmaf(wih1[k + 2], h0c[k + 2], a2);
                a3 = fmaf(wih1[k + 3], h0c[k + 3], a3);
            }
            const float* h1p = &h1buf[rd][half * 64];
            #pragma unroll
            for (int k = 0; k < 64; k += 4) {
                a0 = fmaf(whh1[k],     h1p[k],     a0);
                a1 = fmaf(whh1[k + 1], h1p[k + 1], a1);
                a2 = fmaf(whh1[k + 2], h1p[k + 2], a2);
                a3 = fmaf(whh1[k + 3], h1p[k + 3], a3);
            }
            float acc = (a0 + a2) + (a1 + a3);
            acc += __shfl_xor(acc, 1);
            if (half == 0) h1buf[wr][j] = fast_tanh(acc + bias1);
        }
        __syncthreads();
    }

    // ---- fc epilogue: final h1 is in h1buf[0] (last write index = SEQ&1^1 ... = 0)
    if (t < NCLS) {
        float acc = b_fc[t];
        const float* wf = W_fc + t * HID;
        #pragma unroll
        for (int k = 0; k < HID; ++k)
            acc = fmaf(wf[k], h1buf[0][k], acc);
        out[b * NCLS + t] = acc;
    }
}

extern "C" void kernel_launch(void* const* d_in, const int* in_sizes, int n_in,
                              void* d_out, int out_size, void* d_ws, size_t ws_size,
                              hipStream_t stream) {
    const float* x     = (const float*)d_in[0];
    const float* W_ih0 = (const float*)d_in[1];
    const float* W_hh0 = (const float*)d_in[2];
    const float* b_ih0 = (const float*)d_in[3];
    const float* b_hh0 = (const float*)d_in[4];
    const float* W_ih1 = (const float*)d_in[5];
    const float* W_hh1 = (const float*)d_in[6];
    const float* b_ih1 = (const float*)d_in[7];
    const float* b_hh1 = (const float*)d_in[8];
    const float* W_fc  = (const float*)d_in[9];
    const float* b_fc  = (const float*)d_in[10];
    float* out = (float*)d_out;

    rnn2_kernel<<<dim3(BATCH), dim3(256), 0, stream>>>(
        x, W_ih0, W_hh0, b_ih0, b_hh0, W_ih1, W_hh1, b_ih1, b_hh1, W_fc, b_fc, out);
}

// Round 2
// 679.121 us; speedup vs baseline: 1.1968x; 1.1968x over previous
//
#include <hip/hip_runtime.h>

#define BATCH 512
#define SEQ   512
#define IN    28
#define HID   128
#define NCLS  10
#define ROWS  2              // batch rows per block
#define PADH  36             // padded quarter stride in floats (32 data + 4 pad, 144B: 16B-aligned, bank-offset 4 per quarter)

__device__ __forceinline__ float fast_tanh(float x) {
    float e = __expf(2.0f * x);
    return 1.0f - 2.0f * __builtin_amdgcn_rcpf(e + 1.0f);
}

__global__ __launch_bounds__(512, 2)
void rnn2_kernel(const float* __restrict__ x,
                 const float* __restrict__ W_ih0, const float* __restrict__ W_hh0,
                 const float* __restrict__ b_ih0, const float* __restrict__ b_hh0,
                 const float* __restrict__ W_ih1, const float* __restrict__ W_hh1,
                 const float* __restrict__ b_ih1, const float* __restrict__ b_hh1,
                 const float* __restrict__ W_fc,  const float* __restrict__ b_fc,
                 float* __restrict__ out)
{
    // 114688 B x-stage + 2x2x144x4 x2 h-buffers = ~119 KB LDS (gfx950 has 160 KB)
    __shared__ __align__(16) float xs[ROWS][SEQ * IN];
    __shared__ __align__(16) float h0buf[2][ROWS][4 * PADH];
    __shared__ __align__(16) float h1buf[2][ROWS][4 * PADH];

    const int t = threadIdx.x;          // 0..511
    const int j = t >> 2;               // hidden unit 0..127
    const int q = t & 3;                // k-quarter 0..3
    const int pj = ((j >> 5) * PADH) + (j & 31);   // padded write slot for unit j

    // ---- stage both batch rows of x into LDS, coalesced float4 (7168 f4 / 512 thr = 14 each)
    {
        const float4* xg = (const float4*)(x + (size_t)blockIdx.x * ROWS * SEQ * IN);
        float4* xl = (float4*)&xs[0][0];
        #pragma unroll
        for (int i = 0; i < (ROWS * SEQ * IN / 4) / 512; ++i)
            xl[t + i * 512] = xg[t + i * 512];
    }

    // ---- weights into registers: 7 + 32 + 32 + 32 = 103 floats/thread
    float wih0[IN / 4], whh0[32], wih1[32], whh1[32];
    {
        const float* p = W_ih0 + j * IN + q * (IN / 4);
        #pragma unroll
        for (int k = 0; k < IN / 4; ++k) wih0[k] = p[k];
    }
    {
        const float* p = W_hh0 + j * HID + q * 32;
        #pragma unroll
        for (int k = 0; k < 32; ++k) whh0[k] = p[k];
    }
    {
        const float* p = W_ih1 + j * HID + q * 32;
        #pragma unroll
        for (int k = 0; k < 32; ++k) wih1[k] = p[k];
    }
    {
        const float* p = W_hh1 + j * HID + q * 32;
        #pragma unroll
        for (int k = 0; k < 32; ++k) whh1[k] = p[k];
    }
    const float bias0 = b_ih0[j] + b_hh0[j];
    const float bias1 = b_ih1[j] + b_hh1[j];

    if (t < 4 * PADH) {
        #pragma unroll
        for (int r = 0; r < ROWS; ++r) {
            h0buf[0][r][t] = 0.0f;
            h1buf[0][r][t] = 0.0f;
        }
    }
    __syncthreads();

    // ---- time loop
    for (int step = 0; step < SEQ; ++step) {
        const int rd = step & 1, wr = rd ^ 1;

        // phase A: h0 = tanh(W_ih0 x_t + W_hh0 h0_prev + bias0)
        {
            float accA[ROWS];
            #pragma unroll
            for (int r = 0; r < ROWS; ++r) {
                float a0 = 0.f, a1 = 0.f, a2 = 0.f, a3 = 0.f;
                const float* xt = &xs[r][step * IN + q * (IN / 4)];
                #pragma unroll
                for (int k = 0; k < IN / 4; ++k) {
                    if ((k & 3) == 0) a0 = fmaf(wih0[k], xt[k], a0);
                    else if ((k & 3) == 1) a1 = fmaf(wih0[k], xt[k], a1);
                    else if ((k & 3) == 2) a2 = fmaf(wih0[k], xt[k], a2);
                    else a3 = fmaf(wih0[k], xt[k], a3);
                }
                const float4* hp = (const float4*)&h0buf[rd][r][q * PADH];
                #pragma unroll
                for (int k4 = 0; k4 < 8; ++k4) {
                    float4 h4 = hp[k4];
                    a0 = fmaf(whh0[k4 * 4 + 0], h4.x, a0);
                    a1 = fmaf(whh0[k4 * 4 + 1], h4.y, a1);
                    a2 = fmaf(whh0[k4 * 4 + 2], h4.z, a2);
                    a3 = fmaf(whh0[k4 * 4 + 3], h4.w, a3);
                }
                float s = (a0 + a2) + (a1 + a3);
                s += __shfl_xor(s, 1);
                s += __shfl_xor(s, 2);
                accA[r] = s;
            }
            if (q == 0) {
                #pragma unroll
                for (int r = 0; r < ROWS; ++r)
                    h0buf[wr][r][pj] = fast_tanh(accA[r] + bias0);
            }
        }
        __syncthreads();

        // phase B: h1 = tanh(W_ih1 h0_new + W_hh1 h1_prev + bias1)
        {
            float accB[ROWS];
            #pragma unroll
            for (int r = 0; r < ROWS; ++r) {
                float a0 = 0.f, a1 = 0.f, a2 = 0.f, a3 = 0.f;
                const float4* g = (const float4*)&h0buf[wr][r][q * PADH];
                const float4* hp = (const float4*)&h1buf[rd][r][q * PADH];
                #pragma unroll
                for (int k4 = 0; k4 < 8; ++k4) {
                    float4 g4 = g[k4];
                    float4 h4 = hp[k4];
                    a0 = fmaf(wih1[k4 * 4 + 0], g4.x, a0);
                    a1 = fmaf(wih1[k4 * 4 + 1], g4.y, a1);
                    a2 = fmaf(wih1[k4 * 4 + 2], g4.z, a2);
                    a3 = fmaf(wih1[k4 * 4 + 3], g4.w, a3);
                    a0 = fmaf(whh1[k4 * 4 + 0], h4.x, a0);
                    a1 = fmaf(whh1[k4 * 4 + 1], h4.y, a1);
                    a2 = fmaf(whh1[k4 * 4 + 2], h4.z, a2);
                    a3 = fmaf(whh1[k4 * 4 + 3], h4.w, a3);
                }
                float s = (a0 + a2) + (a1 + a3);
                s += __shfl_xor(s, 1);
                s += __shfl_xor(s, 2);
                accB[r] = s;
            }
            if (q == 0) {
                #pragma unroll
                for (int r = 0; r < ROWS; ++r)
                    h1buf[wr][r][pj] = fast_tanh(accB[r] + bias1);
            }
        }
        __syncthreads();
    }

    // ---- fc epilogue: final h1 in slot 0 (step 511: rd=1, wr=0)
    if (t < ROWS * NCLS) {
        const int r = t / NCLS, c = t % NCLS;
        float acc = b_fc[c];
        const float* wf = W_fc + c * HID;
        #pragma unroll 4
        for (int k = 0; k < HID; ++k)
            acc = fmaf(wf[k], h1buf[0][r][((k >> 5) * PADH) + (k & 31)], acc);
        out[(blockIdx.x * ROWS + r) * NCLS + c] = acc;
    }
}

extern "C" void kernel_launch(void* const* d_in, const int* in_sizes, int n_in,
                              void* d_out, int out_size, void* d_ws, size_t ws_size,
                              hipStream_t stream) {
    const float* x     = (const float*)d_in[0];
    const float* W_ih0 = (const float*)d_in[1];
    const float* W_hh0 = (const float*)d_in[2];
    const float* b_ih0 = (const float*)d_in[3];
    const float* b_hh0 = (const float*)d_in[4];
    const float* W_ih1 = (const float*)d_in[5];
    const float* W_hh1 = (const float*)d_in[6];
    const float* b_ih1 = (const float*)d_in[7];
    const float* b_hh1 = (const float*)d_in[8];
    const float* W_fc  = (const float*)d_in[9];
    const float* b_fc  = (const float*)d_in[10];
    float* out = (float*)d_out;

    rnn2_kernel<<<dim3(BATCH / ROWS), dim3(512), 0, stream>>>(
        x, W_ih0, W_hh0, b_ih0, b_hh0, W_ih1, W_hh1, b_ih1, b_hh1, W_fc, b_fc, out);
}

// Round 4
// 657.941 us; speedup vs baseline: 1.2353x; 1.0322x over previous
//
#include <hip/hip_runtime.h>

#define BATCH 512
#define SEQ   512
#define IN    28
#define HID   128
#define NCLS  10
#define ROWS  2
#define PAD20(k) (((k) >> 4) * 20 + ((k) & 15))   // 16-float slice padded to 20

__device__ __forceinline__ float fast_tanh(float x) {
    float e = __expf(2.0f * x);
    return 1.0f - 2.0f * __builtin_amdgcn_rcpf(e + 1.0f);
}

template<int CTRL>
__device__ __forceinline__ float dpp_add(float v) {
    int n = __builtin_amdgcn_update_dpp(0, __float_as_int(v), CTRL, 0xF, 0xF, true);
    return v + __int_as_float(n);
}
// sum over the 8 lanes of a unit; valid in lanes with (t&7)==0 (also lanes 1-3 of each 8)
// NOTE: DPP row_ror:N reads from lane (i-N)&15 (data moves toward higher lanes),
// so to pull lane i+4 we need row_ror:12 (0x12C), NOT row_ror:4.
__device__ __forceinline__ float reduce8(float v) {
    v = dpp_add<0xB1>(v);    // quad_perm [1,0,3,2] : xor 1
    v = dpp_add<0x4E>(v);    // quad_perm [2,3,0,1] : xor 2
    v = dpp_add<0x12C>(v);   // row_ror:12 : lane i += lane (i+4)&15  (other quad of this 8-group)
    return v;
}

__global__ __launch_bounds__(1024)
void rnn2_kernel(const float* __restrict__ x,
                 const float* __restrict__ W_ih0, const float* __restrict__ W_hh0,
                 const float* __restrict__ b_ih0, const float* __restrict__ b_hh0,
                 const float* __restrict__ W_ih1, const float* __restrict__ W_hh1,
                 const float* __restrict__ b_ih1, const float* __restrict__ b_hh1,
                 const float* __restrict__ W_fc,  const float* __restrict__ b_fc,
                 float* __restrict__ out)
{
    // 8 slices of 16 floats, each padded to 20 -> slice base banks {0,20,8,28,16,4,24,12}: all 32 banks once
    __shared__ __align__(16) float h0buf[2][ROWS][8 * 20];
    __shared__ __align__(16) float h1buf[2][ROWS][8 * 20];

    const int t  = threadIdx.x;      // 0..1023
    const int j  = t >> 3;           // unit 0..127
    const int sl = t & 7;            // k-slice 0..7 (16 k each)

    // ---- weights: 4 + 16 + 16 + 16 = 52 floats/thread, shared across both rows
    float wih0[4], whh0[16], wih1[16], whh1[16];
    {
        if (sl < 7) {
            const float* p = W_ih0 + j * IN + sl * 4;
            #pragma unroll
            for (int k = 0; k < 4; ++k) wih0[k] = p[k];
        } else {
            #pragma unroll
            for (int k = 0; k < 4; ++k) wih0[k] = 0.0f;
        }
    }
    {
        const float* p = W_hh0 + j * HID + sl * 16;
        #pragma unroll
        for (int k = 0; k < 16; ++k) whh0[k] = p[k];
    }
    {
        const float* p = W_ih1 + j * HID + sl * 16;
        #pragma unroll
        for (int k = 0; k < 16; ++k) wih1[k] = p[k];
    }
    {
        const float* p = W_hh1 + j * HID + sl * 16;
        #pragma unroll
        for (int k = 0; k < 16; ++k) whh1[k] = p[k];
    }
    const float bias0 = b_ih0[j] + b_hh0[j];
    const float bias1 = b_ih1[j] + b_hh1[j];

    if (t < 8 * 20) {
        #pragma unroll
        for (int r = 0; r < ROWS; ++r) {
            h0buf[0][r][t] = 0.0f;
            h1buf[0][r][t] = 0.0f;
        }
    }

    // ---- x: direct from global, float4/slice, software-prefetch one step ahead
    const int xoff = (sl < 7) ? sl * 4 : 0;      // sl==7 has zero weights; clamp addr in-bounds
    const float* xbase[ROWS];
    float4 xcur[ROWS];
    #pragma unroll
    for (int r = 0; r < ROWS; ++r) {
        xbase[r] = x + ((size_t)(blockIdx.x * ROWS + r) * SEQ) * IN + xoff;
        xcur[r] = *(const float4*)(xbase[r]);    // step 0
    }

    __syncthreads();

    const int wslot = PAD20(j);   // write slot for unit j

    for (int step = 0; step < SEQ; ++step) {
        const int rd = step & 1, wr = rd ^ 1;
        const int nxt = (step < SEQ - 1) ? (step + 1) * IN : step * IN;

        // ---- phase A: h0 = tanh(W_ih0 x_t + W_hh0 h0_prev + bias0)
        float accA[ROWS];
        float4 xnxt[ROWS];
        #pragma unroll
        for (int r = 0; r < ROWS; ++r) {
            xnxt[r] = *(const float4*)(xbase[r] + nxt);   // prefetch next step
            const float4* hp = (const float4*)&h0buf[rd][r][sl * 20];
            float4 h0v = hp[0], h1v = hp[1], h2v = hp[2], h3v = hp[3];
            float a0, a1, a2, a3;
            a0 = wih0[0] * xcur[r].x;
            a1 = wih0[1] * xcur[r].y;
            a2 = wih0[2] * xcur[r].z;
            a3 = wih0[3] * xcur[r].w;
            a0 = fmaf(whh0[ 0], h0v.x, a0); a1 = fmaf(whh0[ 1], h0v.y, a1);
            a2 = fmaf(whh0[ 2], h0v.z, a2); a3 = fmaf(whh0[ 3], h0v.w, a3);
            a0 = fmaf(whh0[ 4], h1v.x, a0); a1 = fmaf(whh0[ 5], h1v.y, a1);
            a2 = fmaf(whh0[ 6], h1v.z, a2); a3 = fmaf(whh0[ 7], h1v.w, a3);
            a0 = fmaf(whh0[ 8], h2v.x, a0); a1 = fmaf(whh0[ 9], h2v.y, a1);
            a2 = fmaf(whh0[10], h2v.z, a2); a3 = fmaf(whh0[11], h2v.w, a3);
            a0 = fmaf(whh0[12], h3v.x, a0); a1 = fmaf(whh0[13], h3v.y, a1);
            a2 = fmaf(whh0[14], h3v.z, a2); a3 = fmaf(whh0[15], h3v.w, a3);
            accA[r] = reduce8((a0 + a2) + (a1 + a3));
            xcur[r] = xnxt[r];
        }
        if (sl == 0) {
            #pragma unroll
            for (int r = 0; r < ROWS; ++r)
                h0buf[wr][r][wslot] = fast_tanh(accA[r] + bias0);
        }
        __syncthreads();

        // ---- phase B: h1 = tanh(W_ih1 h0_new + W_hh1 h1_prev + bias1)
        float accB[ROWS];
        #pragma unroll
        for (int r = 0; r < ROWS; ++r) {
            const float4* gp = (const float4*)&h0buf[wr][r][sl * 20];
            const float4* hp = (const float4*)&h1buf[rd][r][sl * 20];
            float4 g0 = gp[0], g1 = gp[1], g2 = gp[2], g3 = gp[3];
            float4 h0v = hp[0], h1v = hp[1], h2v = hp[2], h3v = hp[3];
            float a0 = 0.f, a1 = 0.f, a2 = 0.f, a3 = 0.f;
            a0 = fmaf(wih1[ 0], g0.x, a0); a1 = fmaf(wih1[ 1], g0.y, a1);
            a2 = fmaf(wih1[ 2], g0.z, a2); a3 = fmaf(wih1[ 3], g0.w, a3);
            a0 = fmaf(wih1[ 4], g1.x, a0); a1 = fmaf(wih1[ 5], g1.y, a1);
            a2 = fmaf(wih1[ 6], g1.z, a2); a3 = fmaf(wih1[ 7], g1.w, a3);
            a0 = fmaf(wih1[ 8], g2.x, a0); a1 = fmaf(wih1[ 9], g2.y, a1);
            a2 = fmaf(wih1[10], g2.z, a2); a3 = fmaf(wih1[11], g2.w, a3);
            a0 = fmaf(wih1[12], g3.x, a0); a1 = fmaf(wih1[13], g3.y, a1);
            a2 = fmaf(wih1[14], g3.z, a2); a3 = fmaf(wih1[15], g3.w, a3);
            a0 = fmaf(whh1[ 0], h0v.x, a0); a1 = fmaf(whh1[ 1], h0v.y, a1);
            a2 = fmaf(whh1[ 2], h0v.z, a2); a3 = fmaf(whh1[ 3], h0v.w, a3);
            a0 = fmaf(whh1[ 4], h1v.x, a0); a1 = fmaf(whh1[ 5], h1v.y, a1);
            a2 = fmaf(whh1[ 6], h1v.z, a2); a3 = fmaf(whh1[ 7], h1v.w, a3);
            a0 = fmaf(whh1[ 8], h2v.x, a0); a1 = fmaf(whh1[ 9], h2v.y, a1);
            a2 = fmaf(whh1[10], h2v.z, a2); a3 = fmaf(whh1[11], h2v.w, a3);
            a0 = fmaf(whh1[12], h3v.x, a0); a1 = fmaf(whh1[13], h3v.y, a1);
            a2 = fmaf(whh1[14], h3v.z, a2); a3 = fmaf(whh1[15], h3v.w, a3);
            accB[r] = reduce8((a0 + a2) + (a1 + a3));
        }
        if (sl == 0) {
            #pragma unroll
            for (int r = 0; r < ROWS; ++r)
                h1buf[wr][r][wslot] = fast_tanh(accB[r] + bias1);
        }
        __syncthreads();
    }

    // ---- fc epilogue: final h1 in buffer 0 (step 511: wr=0)
    if (t < ROWS * NCLS) {
        const int r = t / NCLS, c = t % NCLS;
        float acc = b_fc[c];
        const float* wf = W_fc + c * HID;
        #pragma unroll 4
        for (int k = 0; k < HID; ++k)
            acc = fmaf(wf[k], h1buf[0][r][PAD20(k)], acc);
        out[(blockIdx.x * ROWS + r) * NCLS + c] = acc;
    }
}

extern "C" void kernel_launch(void* const* d_in, const int* in_sizes, int n_in,
                              void* d_out, int out_size, void* d_ws, size_t ws_size,
                              hipStream_t stream) {
    const float* x     = (const float*)d_in[0];
    const float* W_ih0 = (const float*)d_in[1];
    const float* W_hh0 = (const float*)d_in[2];
    const float* b_ih0 = (const float*)d_in[3];
    const float* b_hh0 = (const float*)d_in[4];
    const float* W_ih1 = (const float*)d_in[5];
    const float* W_hh1 = (const float*)d_in[6];
    const float* b_ih1 = (const float*)d_in[7];
    const float* b_hh1 = (const float*)d_in[8];
    const float* W_fc  = (const float*)d_in[9];
    const float* b_fc  = (const float*)d_in[10];
    float* out = (float*)d_out;

    rnn2_kernel<<<dim3(BATCH / ROWS), dim3(1024), 0, stream>>>(
        x, W_ih0, W_hh0, b_ih0, b_hh0, W_ih1, W_hh1, b_ih1, b_hh1, W_fc, b_fc, out);
}